// Round 5
// baseline (240.729 us; speedup 1.0000x reference)
//
#include <hip/hip_runtime.h>
#include <hip/hip_bf16.h>

// NeighborAttention on MI355X. fp32 in/out, int32 mask.
// KEY INSIGHT (R0): query = broadcast of masked neighbor-mean -> all seq
// positions share one query per (b,h). Attention collapses to GEMV-scale work.
// R6/R7 POST-MORTEM: device-wide software barriers cost ~40us EACH on MI355X.
// R9 POST-MORTEM: fused k_swp @256 threads spilled -> 142.8us, VALUBusy 0.19%.
// R10/R11 POST-MORTEM: 1024-thr rebuild fixed the spill (k_swp now <41us,
// absent from top-5) but total only 182->173us. Dispatch sum (~50-80us) no
// longer explains dur_us: ~90-120us is spread across small dispatches, gaps,
// and per-iteration reset work. Regime shift: launch count + total dispatch
// footprint is the lever now, not per-kernel compute.
// R12: kill k_xwred + the 33 MB nump round-trip. k_swp phase C atomicAdds
// weighted-pool partials directly into xw (device-scope fp32 atomics native
// on CDNA; ~4.2M atomics) and den; k_prep zeroes xw/den (folded, no extra
// launch); k_vctx folds the 1/den scale into the V-GEMV epilogue. 6 -> 5
// launches.
// R13 (this round): R12 bench never ran (GPU acquisition timeout) -> resubmit
// R12 UNCHANGED to measure the atomic-reduction hypothesis before stacking.

#define DIM  1024
#define NH   16
#define HD   64
#define BS   8
#define SEQ  1024
#define NNB  50

// workspace offsets (floats), all 16B-aligned
#define OF_P     16        // p:   128*1024
#define OF_XW    131088    // xw:  128*1024 (atomic num accumulator)
#define OF_DEN   262160    // den: 128      (atomic den accumulator)
#define OF_CTX   262304    // ctx: 8*1024
#define OF_OUTR  270512    // outr:8*1024

// ---------------- K1: fused neighbor-pool + q + p, one block per (h,b) -------
// Also zeroes the xw/den atomic accumulators (runs before k_swp, stream order).
__global__ void k_prep(const float* __restrict__ xnb, const float* __restrict__ nm,
                       const float* __restrict__ qw, const float* __restrict__ qb,
                       const float* __restrict__ kw, float* __restrict__ p,
                       float* __restrict__ xw, float* __restrict__ den){
  int h = blockIdx.x & 15, b = blockIdx.x >> 4;
  int tid = threadIdx.x, wv = tid >> 6, ln = tid & 63;
  {  // zero the atomic accumulators: 32768 threads x 16B = 512KB = xw exactly
    int gid = blockIdx.x*256 + tid;
    float4 z = {0.f,0.f,0.f,0.f};
    *(float4*)(xw + (size_t)gid*4) = z;
    if (gid < BS*NH) den[gid] = 0.f;
  }
  __shared__ float xnl[1024];
  __shared__ float qp[256];
  __shared__ float ql[64];
  {  // masked neighbor mean
    int d = tid*4;
    float4 acc = {0,0,0,0}; float wsum = 0.f;
    #pragma unroll 10
    for (int n=0; n<NNB; n++){
      float w = nm[b*NNB + n];
      float4 v = *(const float4*)(xnb + (size_t)(b*NNB + n)*DIM + d);
      acc.x += w*v.x; acc.y += w*v.y; acc.z += w*v.z; acc.w += w*v.w;
      wsum += w;
    }
    float inv = 1.f/wsum;
    acc.x*=inv; acc.y*=inv; acc.z*=inv; acc.w*=inv;
    *(float4*)(xnl + d) = acc;
  }
  __syncthreads();
  {  // q partial: lane ln -> row h*64+ln of qw, wave wv -> 256-d chunk
    const float* qrow = qw + (size_t)(h*HD + ln)*DIM + wv*256;
    const float* xrow = xnl + wv*256;
    float part = 0.f;
    #pragma unroll 16
    for (int i=0; i<64; i++){
      float4 a = *(const float4*)(qrow + i*4);
      float4 c = *(const float4*)(xrow + i*4);
      part += a.x*c.x + a.y*c.y + a.z*c.z + a.w*c.w;
    }
    qp[wv*64 + ln] = part;
  }
  __syncthreads();
  if (wv == 0){
    float qv = qp[ln] + qp[64+ln] + qp[128+ln] + qp[192+ln];
    ql[ln] = (qv + qb[h*HD + ln]) * 0.125f;
  }
  __syncthreads();
  {  // p[b,h,d] = sum_j ql[j]*kw[h*64+j,d]
    int d = tid*4;
    float4 acc = {0,0,0,0};
    #pragma unroll 8
    for (int j=0; j<HD; j++){
      float qj = ql[j];
      float4 kv = *(const float4*)(kw + (size_t)(h*HD + j)*DIM + d);
      acc.x += qj*kv.x; acc.y += qj*kv.y; acc.z += qj*kv.z; acc.w += qj*kv.w;
    }
    *(float4*)(p + (size_t)(b*NH + h)*DIM + d) = acc;
  }
}

// ---------------- K2: fused scores + exp + weighted pool (atomic out) -------
// grid (8 b, 32 sc), block 1024 = 16 waves. Block: 32 seq rows x 16 heads.
// Phase A: wave wv -> (hg = wv&3 head-group, sq = wv>>2 s-quarter of 8 rows).
//   p for 4 heads in registers; x direct from global (L1/L2-hot across the
//   4 hg-waves); shfl_xor butterfly completes the 1024-d dot.
// Phase B: 512 threads apply mask*exp; den partial atomicAdd'd per head.
// Phase C: wave wv -> (hg2 = wv>>2, dc = wv&3); 4-head float4 accumulators;
//   atomicAdd into xw (cross-block reduction in place; no nump slabs).
__global__ __launch_bounds__(1024, 4)
void k_swp(const float* __restrict__ x, const float* __restrict__ p,
           const int* __restrict__ mask,
           float* __restrict__ xw, float* __restrict__ den){
  int b = blockIdx.x, sc = blockIdx.y;
  int s0 = sc * 32;
  int tid = threadIdx.x, wv = tid >> 6, ln = tid & 63;
  __shared__ float wf[32*20];          // [s][h] stride-20, 2.5 KB

  int hg = wv & 3, sq = wv >> 2;
  float acc[8][4];
  #pragma unroll
  for (int i=0; i<8; i++){ acc[i][0]=0.f; acc[i][1]=0.f; acc[i][2]=0.f; acc[i][3]=0.f; }

  #pragma unroll 1
  for (int kc=0; kc<4; kc++){
    int d = kc*256 + ln*4;
    const float* pb = p + (size_t)(b*NH + hg*4)*DIM + d;
    float4 pr0 = *(const float4*)(pb);
    float4 pr1 = *(const float4*)(pb +   (size_t)DIM);
    float4 pr2 = *(const float4*)(pb + 2*(size_t)DIM);
    float4 pr3 = *(const float4*)(pb + 3*(size_t)DIM);
    const float* xb = x + (size_t)(b*SEQ + s0 + sq*8)*DIM + d;
    #pragma unroll
    for (int sb=0; sb<8; sb+=4){
      float4 xr[4];
      #pragma unroll
      for (int u=0; u<4; u++)
        xr[u] = *(const float4*)(xb + (size_t)(sb+u)*DIM);
      #pragma unroll
      for (int u=0; u<4; u++){
        acc[sb+u][0] += xr[u].x*pr0.x + xr[u].y*pr0.y + xr[u].z*pr0.z + xr[u].w*pr0.w;
        acc[sb+u][1] += xr[u].x*pr1.x + xr[u].y*pr1.y + xr[u].z*pr1.z + xr[u].w*pr1.w;
        acc[sb+u][2] += xr[u].x*pr2.x + xr[u].y*pr2.y + xr[u].z*pr2.z + xr[u].w*pr2.w;
        acc[sb+u][3] += xr[u].x*pr3.x + xr[u].y*pr3.y + xr[u].z*pr3.z + xr[u].w*pr3.w;
      }
    }
  }
  // butterfly: complete each (s,h) dot across the 64 lanes' d-slices
  #pragma unroll
  for (int off=1; off<64; off<<=1){
    #pragma unroll
    for (int si=0; si<8; si++){
      acc[si][0] += __shfl_xor(acc[si][0], off, 64);
      acc[si][1] += __shfl_xor(acc[si][1], off, 64);
      acc[si][2] += __shfl_xor(acc[si][2], off, 64);
      acc[si][3] += __shfl_xor(acc[si][3], off, 64);
    }
  }
  if (ln == 0){
    #pragma unroll
    for (int si=0; si<8; si++){
      float4 v; v.x = acc[si][0]; v.y = acc[si][1]; v.z = acc[si][2]; v.w = acc[si][3];
      *(float4*)(wf + (sq*8 + si)*20 + hg*4) = v;
    }
  }
  __syncthreads();
  if (tid < 512){                      // phase B: e = mask * exp(score), in place
    int s = tid >> 4, h = tid & 15;
    float sv = wf[s*20 + h];
    wf[s*20 + h] = mask[b*SEQ + s0 + s] ? __expf(sv) : 0.f;
  }
  __syncthreads();
  if (tid < 16){                       // den partial per head -> atomic
    float dsum = 0.f;
    #pragma unroll
    for (int ss=0; ss<32; ss++) dsum += wf[ss*20 + tid];
    atomicAdd(&den[b*NH + tid], dsum);
  }
  // phase C: weighted pool. wave wv -> heads hg2*4..+3, d chunk dc*256..+255.
  int hg2 = wv >> 2, dc = wv & 3;
  int d = dc*256 + ln*4;
  const float* xbase = x + (size_t)(b*SEQ + s0)*DIM + d;
  float4 a0={0,0,0,0}, a1={0,0,0,0}, a2={0,0,0,0}, a3={0,0,0,0};
  #pragma unroll 2
  for (int sb=0; sb<32; sb+=4){
    float4 xq[4];
    #pragma unroll
    for (int u=0; u<4; u++)
      xq[u] = *(const float4*)(xbase + (size_t)(sb+u)*DIM);
    #pragma unroll
    for (int u=0; u<4; u++){
      float4 w = *(const float4*)(wf + (sb+u)*20 + hg2*4);   // wave-uniform bcast
      a0.x += xq[u].x*w.x; a0.y += xq[u].y*w.x; a0.z += xq[u].z*w.x; a0.w += xq[u].w*w.x;
      a1.x += xq[u].x*w.y; a1.y += xq[u].y*w.y; a1.z += xq[u].z*w.y; a1.w += xq[u].w*w.y;
      a2.x += xq[u].x*w.z; a2.y += xq[u].y*w.z; a2.z += xq[u].z*w.z; a2.w += xq[u].w*w.z;
      a3.x += xq[u].x*w.w; a3.y += xq[u].y*w.w; a3.z += xq[u].z*w.w; a3.w += xq[u].w*w.w;
    }
  }
  float* dst = xw + (size_t)(b*NH + hg2*4)*DIM + d;
  atomicAdd(dst + 0, a0.x); atomicAdd(dst + 1, a0.y);
  atomicAdd(dst + 2, a0.z); atomicAdd(dst + 3, a0.w);
  dst += DIM;
  atomicAdd(dst + 0, a1.x); atomicAdd(dst + 1, a1.y);
  atomicAdd(dst + 2, a1.z); atomicAdd(dst + 3, a1.w);
  dst += DIM;
  atomicAdd(dst + 0, a2.x); atomicAdd(dst + 1, a2.y);
  atomicAdd(dst + 2, a2.z); atomicAdd(dst + 3, a2.w);
  dst += DIM;
  atomicAdd(dst + 0, a3.x); atomicAdd(dst + 1, a3.y);
  atomicAdd(dst + 2, a3.z); atomicAdd(dst + 3, a3.w);
}

// ---------------- K3: ctx[b,jo] = (xw[b,h,:].vw[jo,:])/den[b,h] + vb[jo] ----
// h = jo>>6 is uniform per block (4 consecutive jo, 64-aligned groups).
__global__ void k_vctx(const float* __restrict__ xw, const float* __restrict__ den,
                       const float* __restrict__ vw, const float* __restrict__ vb,
                       float* __restrict__ ctx){
  int wv = threadIdx.x >> 6, ln = threadIdx.x & 63;
  int jo = blockIdx.x*4 + wv;
  int h  = jo >> 6;
  float acc[BS] = {0,0,0,0,0,0,0,0};
  #pragma unroll
  for (int i=0; i<4; i++){
    int d = ln*4 + 256*i;
    float4 vv = *(const float4*)(vw + (size_t)jo*DIM + d);
    #pragma unroll
    for (int b=0; b<BS; b++){
      float4 xv = *(const float4*)(xw + (size_t)(b*NH + h)*DIM + d);
      acc[b] += vv.x*xv.x + vv.y*xv.y + vv.z*xv.z + vv.w*xv.w;
    }
  }
  #pragma unroll
  for (int off=32; off>=1; off>>=1){
    #pragma unroll
    for (int b=0; b<BS; b++) acc[b] += __shfl_down(acc[b], off, 64);
  }
  if (ln == 0){
    float bias = vb[jo];
    #pragma unroll
    for (int b=0; b<BS; b++)
      ctx[b*DIM + jo] = acc[b] / den[b*NH + h] + bias;
  }
}

// ---------------- K4: out_row[b,i] = ctx[b,:].ow[i,:] + ob[i] ----------------
__global__ void k_outrow(const float* __restrict__ ctx, const float* __restrict__ ow,
                         const float* __restrict__ ob, float* __restrict__ outr){
  int wv = threadIdx.x >> 6, ln = threadIdx.x & 63;
  int io = blockIdx.x*4 + wv;
  float acc[BS] = {0,0,0,0,0,0,0,0};
  #pragma unroll
  for (int i=0; i<4; i++){
    int d = ln*4 + 256*i;
    float4 wt = *(const float4*)(ow + (size_t)io*DIM + d);
    #pragma unroll
    for (int b=0; b<BS; b++){
      float4 cv = *(const float4*)(ctx + b*DIM + d);
      acc[b] += wt.x*cv.x + wt.y*cv.y + wt.z*cv.z + wt.w*cv.w;
    }
  }
  #pragma unroll
  for (int off=32; off>=1; off>>=1){
    #pragma unroll
    for (int b=0; b<BS; b++) acc[b] += __shfl_down(acc[b], off, 64);
  }
  if (ln == 0){
    float bias = ob[io];
    #pragma unroll
    for (int b=0; b<BS; b++) outr[b*DIM + io] = acc[b] + bias;
  }
}

// ---------------- K5: out[b,s,:] = LN(out_row[b]+x[b,s,:])*g + beta ---------
__global__ void k_ln(const float* __restrict__ x, const float* __restrict__ outr,
                     const float* __restrict__ g, const float* __restrict__ bt,
                     float* __restrict__ out){
  int row = blockIdx.x;
  int b = row >> 10;
  size_t base = (size_t)row * DIM;
  int tid = threadIdx.x;
  float4 xv = ((const float4*)(x + base))[tid];
  float4 ov = ((const float4*)(outr + (size_t)b*DIM))[tid];
  float4 h;
  h.x = xv.x + ov.x; h.y = xv.y + ov.y; h.z = xv.z + ov.z; h.w = xv.w + ov.w;
  float s  = h.x + h.y + h.z + h.w;
  float s2 = h.x*h.x + h.y*h.y + h.z*h.z + h.w*h.w;
  #pragma unroll
  for (int off=32; off>=1; off>>=1){
    s  += __shfl_xor(s,  off, 64);
    s2 += __shfl_xor(s2, off, 64);
  }
  __shared__ float r1[4], r2[4];
  int wv = tid >> 6, ln = tid & 63;
  if (ln == 0){ r1[wv] = s; r2[wv] = s2; }
  __syncthreads();
  s  = r1[0] + r1[1] + r1[2] + r1[3];
  s2 = r2[0] + r2[1] + r2[2] + r2[3];
  float mu   = s  * (1.f/1024.f);
  float var  = s2 * (1.f/1024.f) - mu*mu;
  float rstd = rsqrtf(var + 1e-12f);
  float4 gv = ((const float4*)g)[tid];
  float4 bv = ((const float4*)bt)[tid];
  float4 y;
  y.x = (h.x - mu)*rstd*gv.x + bv.x;
  y.y = (h.y - mu)*rstd*gv.y + bv.y;
  y.z = (h.z - mu)*rstd*gv.z + bv.z;
  y.w = (h.w - mu)*rstd*gv.w + bv.w;
  ((float4*)(out + base))[tid] = y;
}

extern "C" void kernel_launch(void* const* d_in, const int* in_sizes, int n_in,
                              void* d_out, int out_size, void* d_ws, size_t ws_size,
                              hipStream_t stream) {
  const float* x    = (const float*)d_in[0];
  const float* xnb  = (const float*)d_in[1];
  const int*   mask = (const int*  )d_in[2];
  const float* nm   = (const float*)d_in[3];
  const float* qw   = (const float*)d_in[4];
  const float* qb   = (const float*)d_in[5];
  const float* kw   = (const float*)d_in[6];
  // d_in[7] = kb: softmax-invariant constant, unused
  const float* vw   = (const float*)d_in[8];
  const float* vb   = (const float*)d_in[9];
  const float* ow   = (const float*)d_in[10];
  const float* ob   = (const float*)d_in[11];
  const float* lng  = (const float*)d_in[12];
  const float* lnb  = (const float*)d_in[13];
  float* out = (float*)d_out;

  float* ws   = (float*)d_ws;              // ~1.1 MB of ~256 MB ws
  float* p    = ws + OF_P;
  float* xw   = ws + OF_XW;                // atomic num accumulator
  float* den  = ws + OF_DEN;               // atomic den accumulator
  float* ctx  = ws + OF_CTX;
  float* outr = ws + OF_OUTR;

  k_prep  <<<128,             256,  0, stream>>>(xnb, nm, qw, qb, kw, p, xw, den);
  k_swp   <<<dim3(BS,32),     1024, 0, stream>>>(x, p, mask, xw, den);
  k_vctx  <<<256,             256,  0, stream>>>(xw, den, vw, vb, ctx);
  k_outrow<<<256,             256,  0, stream>>>(ctx, ow, ob, outr);
  k_ln    <<<BS*SEQ,          256,  0, stream>>>(x, outr, lng, lnb, out);
}

// Round 8
// 198.518 us; speedup vs baseline: 1.2126x; 1.2126x over previous
//
#include <hip/hip_runtime.h>
#include <hip/hip_bf16.h>

// NeighborAttention on MI355X. fp32 in/out, int32 mask.
// KEY INSIGHT (R0): query = broadcast of masked neighbor-mean -> all seq
// positions share one query per (b,h). Attention collapses to GEMV-scale work.
// R6/R7 POST-MORTEM: device-wide software barriers cost ~40us EACH on MI355X.
// R9 POST-MORTEM: fused k_swp @256 threads spilled -> 142.8us, VALUBusy 0.19%.
// R10/R11 POST-MORTEM: spill fixed (k_swp <41us) but total only 182->173us;
// launch count + dispatch footprint is the lever, not per-kernel compute.
// R12/R13 POST-MORTEM (measured 240.7us): device-scope fp32 atomicAdd executes
// past the non-coherent per-XCD L2s: 4.19M atomics -> k_swp 107us, WRITE_SIZE
// 65.5MB (4x line-RMW amplification), ~25ns/atomic + 32-way contention.
// LESSON: never atomic-reduce MB-scale data cross-XCD; slab or owner-computes.
// R14: the cross-block dep is only e[s,h] (512 KB). k_swp keeps phases A+B,
// writes e + denp (0.5 MB, not 33 MB nump slabs, not atomics). New k_pool:
// owner-computes grid (b, d-chunk), each block loops ALL 1024 s with e[b]
// staged in LDS (64 KB) -> writes xw pre-normalized (1/den folded). k_ctx
// stays pure GEMV. 6 launches, ~1 MB inter-kernel traffic.
// R15/R16: benches never ran (GPU acquisition timeouts) -> resubmit R14
// UNCHANGED. Note: no further fusion is stackable anyway — every adjacent
// kernel pair has a cross-block dep that would need a ~40us device barrier;
// 6 launches is dependency-minimal for this decomposition.

#define DIM  1024
#define NH   16
#define HD   64
#define BS   8
#define SEQ  1024
#define NNB  50

// workspace offsets (floats), all 16B-aligned
#define OF_P     16        // p:    128*1024
#define OF_E     131088    // e:    8*1024*16
#define OF_DENP  262160    // denp: 32*8*16
#define OF_XW    266256    // xw:   128*1024 (pre-normalized pool)
#define OF_CTX   397328    // ctx:  8*1024
#define OF_OUTR  405520    // outr: 8*1024

// ---------------- K1: fused neighbor-pool + q + p, one block per (h,b) -------
__global__ void k_prep(const float* __restrict__ xnb, const float* __restrict__ nm,
                       const float* __restrict__ qw, const float* __restrict__ qb,
                       const float* __restrict__ kw, float* __restrict__ p){
  int h = blockIdx.x & 15, b = blockIdx.x >> 4;
  int tid = threadIdx.x, wv = tid >> 6, ln = tid & 63;
  __shared__ float xnl[1024];
  __shared__ float qp[256];
  __shared__ float ql[64];
  {  // masked neighbor mean
    int d = tid*4;
    float4 acc = {0,0,0,0}; float wsum = 0.f;
    #pragma unroll 10
    for (int n=0; n<NNB; n++){
      float w = nm[b*NNB + n];
      float4 v = *(const float4*)(xnb + (size_t)(b*NNB + n)*DIM + d);
      acc.x += w*v.x; acc.y += w*v.y; acc.z += w*v.z; acc.w += w*v.w;
      wsum += w;
    }
    float inv = 1.f/wsum;
    acc.x*=inv; acc.y*=inv; acc.z*=inv; acc.w*=inv;
    *(float4*)(xnl + d) = acc;
  }
  __syncthreads();
  {  // q partial: lane ln -> row h*64+ln of qw, wave wv -> 256-d chunk
    const float* qrow = qw + (size_t)(h*HD + ln)*DIM + wv*256;
    const float* xrow = xnl + wv*256;
    float part = 0.f;
    #pragma unroll 16
    for (int i=0; i<64; i++){
      float4 a = *(const float4*)(qrow + i*4);
      float4 c = *(const float4*)(xrow + i*4);
      part += a.x*c.x + a.y*c.y + a.z*c.z + a.w*c.w;
    }
    qp[wv*64 + ln] = part;
  }
  __syncthreads();
  if (wv == 0){
    float qv = qp[ln] + qp[64+ln] + qp[128+ln] + qp[192+ln];
    ql[ln] = (qv + qb[h*HD + ln]) * 0.125f;
  }
  __syncthreads();
  {  // p[b,h,d] = sum_j ql[j]*kw[h*64+j,d]
    int d = tid*4;
    float4 acc = {0,0,0,0};
    #pragma unroll 8
    for (int j=0; j<HD; j++){
      float qj = ql[j];
      float4 kv = *(const float4*)(kw + (size_t)(h*HD + j)*DIM + d);
      acc.x += qj*kv.x; acc.y += qj*kv.y; acc.z += qj*kv.z; acc.w += qj*kv.w;
    }
    *(float4*)(p + (size_t)(b*NH + h)*DIM + d) = acc;
  }
}

// ---------------- K2: scores + exp -> e, denp (phases A+B only) -------------
// grid (8 b, 32 sc), block 1024 = 16 waves. Block: 32 seq rows x 16 heads.
// Phase A: wave wv -> (hg = wv&3 head-group, sq = wv>>2 s-quarter of 8 rows).
//   p for 4 heads in registers; x direct from global (L1/L2-hot across the
//   4 hg-waves); shfl_xor butterfly completes the 1024-d dot.
// Phase B: 512 threads compute e = mask*exp(score), write to global e
//   (contiguous 2 KB) and wf; den partial per head -> denp slab (no atomics).
__global__ __launch_bounds__(1024, 4)
void k_swp(const float* __restrict__ x, const float* __restrict__ p,
           const int* __restrict__ mask,
           float* __restrict__ e, float* __restrict__ denp){
  int b = blockIdx.x, sc = blockIdx.y;
  int s0 = sc * 32;
  int tid = threadIdx.x, wv = tid >> 6, ln = tid & 63;
  __shared__ float wf[32*20];          // [s][h] stride-20, 2.5 KB

  int hg = wv & 3, sq = wv >> 2;
  float acc[8][4];
  #pragma unroll
  for (int i=0; i<8; i++){ acc[i][0]=0.f; acc[i][1]=0.f; acc[i][2]=0.f; acc[i][3]=0.f; }

  #pragma unroll 1
  for (int kc=0; kc<4; kc++){
    int d = kc*256 + ln*4;
    const float* pb = p + (size_t)(b*NH + hg*4)*DIM + d;
    float4 pr0 = *(const float4*)(pb);
    float4 pr1 = *(const float4*)(pb +   (size_t)DIM);
    float4 pr2 = *(const float4*)(pb + 2*(size_t)DIM);
    float4 pr3 = *(const float4*)(pb + 3*(size_t)DIM);
    const float* xb = x + (size_t)(b*SEQ + s0 + sq*8)*DIM + d;
    #pragma unroll
    for (int sb=0; sb<8; sb+=4){
      float4 xr[4];
      #pragma unroll
      for (int u=0; u<4; u++)
        xr[u] = *(const float4*)(xb + (size_t)(sb+u)*DIM);
      #pragma unroll
      for (int u=0; u<4; u++){
        acc[sb+u][0] += xr[u].x*pr0.x + xr[u].y*pr0.y + xr[u].z*pr0.z + xr[u].w*pr0.w;
        acc[sb+u][1] += xr[u].x*pr1.x + xr[u].y*pr1.y + xr[u].z*pr1.z + xr[u].w*pr1.w;
        acc[sb+u][2] += xr[u].x*pr2.x + xr[u].y*pr2.y + xr[u].z*pr2.z + xr[u].w*pr2.w;
        acc[sb+u][3] += xr[u].x*pr3.x + xr[u].y*pr3.y + xr[u].z*pr3.z + xr[u].w*pr3.w;
      }
    }
  }
  // butterfly: complete each (s,h) dot across the 64 lanes' d-slices
  #pragma unroll
  for (int off=1; off<64; off<<=1){
    #pragma unroll
    for (int si=0; si<8; si++){
      acc[si][0] += __shfl_xor(acc[si][0], off, 64);
      acc[si][1] += __shfl_xor(acc[si][1], off, 64);
      acc[si][2] += __shfl_xor(acc[si][2], off, 64);
      acc[si][3] += __shfl_xor(acc[si][3], off, 64);
    }
  }
  if (ln == 0){
    #pragma unroll
    for (int si=0; si<8; si++){
      float4 v; v.x = acc[si][0]; v.y = acc[si][1]; v.z = acc[si][2]; v.w = acc[si][3];
      *(float4*)(wf + (sq*8 + si)*20 + hg*4) = v;
    }
  }
  __syncthreads();
  if (tid < 512){                      // phase B: e = mask * exp(score)
    int s = tid >> 4, h = tid & 15;
    float sv = wf[s*20 + h];
    float ev = mask[b*SEQ + s0 + s] ? __expf(sv) : 0.f;
    wf[s*20 + h] = ev;
    e[(size_t)(b*SEQ + s0)*NH + tid] = ev;   // [b][s][h], contiguous 2 KB
  }
  __syncthreads();
  if (tid < 16){                       // den partial per head -> slab
    float dsum = 0.f;
    #pragma unroll
    for (int ss=0; ss<32; ss++) dsum += wf[ss*20 + tid];
    denp[(sc*BS + b)*NH + tid] = dsum;
  }
}

// ---------------- K3: owner-computes weighted pool ---------------------------
// grid (8 b, 4 dc), block 1024 = 16 waves (hg = wv&3 head-group, sq = wv>>2
// s-quarter of 256 rows). Lane owns d = dc*256 + ln*4 exclusively; loops its
// 256 s with e[b] staged in LDS (wave-uniform broadcast reads). Cross-sq
// reduction in LDS (reusing the e buffer), 1/den applied, xw written
// pre-normalized. No cross-block reduction, no atomics.
__global__ __launch_bounds__(1024, 4)
void k_pool(const float* __restrict__ x, const float* __restrict__ e,
            const float* __restrict__ denp, float* __restrict__ xw){
  int b = blockIdx.x, dc = blockIdx.y;
  int tid = threadIdx.x, wv = tid >> 6, ln = tid & 63;
  int hg = wv & 3, sq = wv >> 2;
  __shared__ float elds[SEQ*NH];       // 64 KB: e[b] as [s][h]; reused as redbuf
  __shared__ float invd[NH];
  const float* eb = e + (size_t)b*SEQ*NH;
  #pragma unroll
  for (int it=0; it<4; it++){          // stage e: 16384 floats via float4
    int idx = it*4096 + tid*4;
    *(float4*)(elds + idx) = *(const float4*)(eb + idx);
  }
  if (tid < NH){                       // den = sum of 32 slab partials
    float dsum = 0.f;
    #pragma unroll
    for (int sc=0; sc<32; sc++) dsum += denp[(sc*BS + b)*NH + tid];
    invd[tid] = 1.f/dsum;
  }
  __syncthreads();
  int d = dc*256 + ln*4;
  const float* xb = x + (size_t)(b*SEQ + sq*256)*DIM + d;
  float4 a0={0,0,0,0}, a1={0,0,0,0}, a2={0,0,0,0}, a3={0,0,0,0};
  #pragma unroll 1
  for (int ss=0; ss<256; ss+=8){
    float4 xq[8];
    #pragma unroll
    for (int u=0; u<8; u++)
      xq[u] = *(const float4*)(xb + (size_t)(ss+u)*DIM);   // 8 loads in flight
    #pragma unroll
    for (int u=0; u<8; u++){
      float4 w = *(const float4*)(elds + (sq*256 + ss + u)*NH + hg*4); // uniform
      a0.x += xq[u].x*w.x; a0.y += xq[u].y*w.x; a0.z += xq[u].z*w.x; a0.w += xq[u].w*w.x;
      a1.x += xq[u].x*w.y; a1.y += xq[u].y*w.y; a1.z += xq[u].z*w.y; a1.w += xq[u].w*w.y;
      a2.x += xq[u].x*w.z; a2.y += xq[u].y*w.z; a2.z += xq[u].z*w.z; a2.w += xq[u].w*w.z;
      a3.x += xq[u].x*w.w; a3.y += xq[u].y*w.w; a3.z += xq[u].z*w.w; a3.w += xq[u].w*w.w;
    }
  }
  __syncthreads();                     // e reads done; reuse elds as redbuf
  float4* red = (float4*)elds;         // [q][wv][ln] float4 = 16384 floats
  red[0*1024 + wv*64 + ln] = a0;
  red[1*1024 + wv*64 + ln] = a1;
  red[2*1024 + wv*64 + ln] = a2;
  red[3*1024 + wv*64 + ln] = a3;
  __syncthreads();
  if (sq == 0){                        // reduce 4 s-quarters, scale, write
    #pragma unroll
    for (int q=0; q<4; q++){
      float4 s = red[q*1024 + (0*4+hg)*64 + ln];
      #pragma unroll
      for (int s4=1; s4<4; s4++){
        float4 t = red[q*1024 + (s4*4+hg)*64 + ln];
        s.x += t.x; s.y += t.y; s.z += t.z; s.w += t.w;
      }
      float iv = invd[hg*4 + q];
      s.x *= iv; s.y *= iv; s.z *= iv; s.w *= iv;
      *(float4*)(xw + (size_t)(b*NH + hg*4 + q)*DIM + d) = s;
    }
  }
}

// ---------------- K4: ctx[b,jo] = xw[b,h(jo),:].vw[jo,:] + vb[jo] ----------
__global__ void k_ctx(const float* __restrict__ xw, const float* __restrict__ vw,
                      const float* __restrict__ vb, float* __restrict__ ctx){
  int wv = threadIdx.x >> 6, ln = threadIdx.x & 63;
  int jo = blockIdx.x*4 + wv;
  int h  = jo >> 6;
  float acc[BS] = {0,0,0,0,0,0,0,0};
  #pragma unroll
  for (int i=0; i<4; i++){
    int d = ln*4 + 256*i;
    float4 vv = *(const float4*)(vw + (size_t)jo*DIM + d);
    #pragma unroll
    for (int b=0; b<BS; b++){
      float4 xv = *(const float4*)(xw + (size_t)(b*NH + h)*DIM + d);
      acc[b] += vv.x*xv.x + vv.y*xv.y + vv.z*xv.z + vv.w*xv.w;
    }
  }
  #pragma unroll
  for (int off=32; off>=1; off>>=1){
    #pragma unroll
    for (int b=0; b<BS; b++) acc[b] += __shfl_down(acc[b], off, 64);
  }
  if (ln == 0){
    float bias = vb[jo];
    #pragma unroll
    for (int b=0; b<BS; b++) ctx[b*DIM + jo] = acc[b] + bias;
  }
}

// ---------------- K5: out_row[b,i] = ctx[b,:].ow[i,:] + ob[i] ----------------
__global__ void k_outrow(const float* __restrict__ ctx, const float* __restrict__ ow,
                         const float* __restrict__ ob, float* __restrict__ outr){
  int wv = threadIdx.x >> 6, ln = threadIdx.x & 63;
  int io = blockIdx.x*4 + wv;
  float acc[BS] = {0,0,0,0,0,0,0,0};
  #pragma unroll
  for (int i=0; i<4; i++){
    int d = ln*4 + 256*i;
    float4 wt = *(const float4*)(ow + (size_t)io*DIM + d);
    #pragma unroll
    for (int b=0; b<BS; b++){
      float4 cv = *(const float4*)(ctx + b*DIM + d);
      acc[b] += wt.x*cv.x + wt.y*cv.y + wt.z*cv.z + wt.w*cv.w;
    }
  }
  #pragma unroll
  for (int off=32; off>=1; off>>=1){
    #pragma unroll
    for (int b=0; b<BS; b++) acc[b] += __shfl_down(acc[b], off, 64);
  }
  if (ln == 0){
    float bias = ob[io];
    #pragma unroll
    for (int b=0; b<BS; b++) outr[b*DIM + io] = acc[b] + bias;
  }
}

// ---------------- K6: out[b,s,:] = LN(out_row[b]+x[b,s,:])*g + beta ---------
__global__ void k_ln(const float* __restrict__ x, const float* __restrict__ outr,
                     const float* __restrict__ g, const float* __restrict__ bt,
                     float* __restrict__ out){
  int row = blockIdx.x;
  int b = row >> 10;
  size_t base = (size_t)row * DIM;
  int tid = threadIdx.x;
  float4 xv = ((const float4*)(x + base))[tid];
  float4 ov = ((const float4*)(outr + (size_t)b*DIM))[tid];
  float4 h;
  h.x = xv.x + ov.x; h.y = xv.y + ov.y; h.z = xv.z + ov.z; h.w = xv.w + ov.w;
  float s  = h.x + h.y + h.z + h.w;
  float s2 = h.x*h.x + h.y*h.y + h.z*h.z + h.w*h.w;
  #pragma unroll
  for (int off=32; off>=1; off>>=1){
    s  += __shfl_xor(s,  off, 64);
    s2 += __shfl_xor(s2, off, 64);
  }
  __shared__ float r1[4], r2[4];
  int wv = tid >> 6, ln = tid & 63;
  if (ln == 0){ r1[wv] = s; r2[wv] = s2; }
  __syncthreads();
  s  = r1[0] + r1[1] + r1[2] + r1[3];
  s2 = r2[0] + r2[1] + r2[2] + r2[3];
  float mu   = s  * (1.f/1024.f);
  float var  = s2 * (1.f/1024.f) - mu*mu;
  float rstd = rsqrtf(var + 1e-12f);
  float4 gv = ((const float4*)g)[tid];
  float4 bv = ((const float4*)bt)[tid];
  float4 y;
  y.x = (h.x - mu)*rstd*gv.x + bv.x;
  y.y = (h.y - mu)*rstd*gv.y + bv.y;
  y.z = (h.z - mu)*rstd*gv.z + bv.z;
  y.w = (h.w - mu)*rstd*gv.w + bv.w;
  ((float4*)(out + base))[tid] = y;
}

extern "C" void kernel_launch(void* const* d_in, const int* in_sizes, int n_in,
                              void* d_out, int out_size, void* d_ws, size_t ws_size,
                              hipStream_t stream) {
  const float* x    = (const float*)d_in[0];
  const float* xnb  = (const float*)d_in[1];
  const int*   mask = (const int*  )d_in[2];
  const float* nm   = (const float*)d_in[3];
  const float* qw   = (const float*)d_in[4];
  const float* qb   = (const float*)d_in[5];
  const float* kw   = (const float*)d_in[6];
  // d_in[7] = kb: softmax-invariant constant, unused
  const float* vw   = (const float*)d_in[8];
  const float* vb   = (const float*)d_in[9];
  const float* ow   = (const float*)d_in[10];
  const float* ob   = (const float*)d_in[11];
  const float* lng  = (const float*)d_in[12];
  const float* lnb  = (const float*)d_in[13];
  float* out = (float*)d_out;

  float* ws   = (float*)d_ws;              // ~1.6 MB of ~256 MB ws
  float* p    = ws + OF_P;
  float* e    = ws + OF_E;                 // exp-weights, 512 KB
  float* denp = ws + OF_DENP;              // 32 x 128 den partials
  float* xw   = ws + OF_XW;                // pre-normalized pool
  float* ctx  = ws + OF_CTX;
  float* outr = ws + OF_OUTR;

  k_prep  <<<128,             256,  0, stream>>>(xnb, nm, qw, qb, kw, p);
  k_swp   <<<dim3(BS,32),     1024, 0, stream>>>(x, p, mask, e, denp);
  k_pool  <<<dim3(BS,4),      1024, 0, stream>>>(x, e, denp, xw);
  k_ctx   <<<256,             256,  0, stream>>>(xw, vw, vb, ctx);
  k_outrow<<<256,             256,  0, stream>>>(ctx, ow, ob, outr);
  k_ln    <<<BS*SEQ,          256,  0, stream>>>(x, outr, lng, lnb, out);
}

// Round 12
// 178.594 us; speedup vs baseline: 1.3479x; 1.1116x over previous
//
#include <hip/hip_runtime.h>
#include <hip/hip_bf16.h>

// NeighborAttention on MI355X. fp32 in/out, int32 mask.
// KEY INSIGHT (R0): query = broadcast of masked neighbor-mean -> all seq
// positions share one query per (b,h). Attention collapses to GEMV-scale work.
// R6/R7 POST-MORTEM: device-wide software barriers cost ~40us EACH on MI355X.
// R9 POST-MORTEM: fused k_swp @256 threads spilled -> 142.8us, VALUBusy 0.19%.
// R10/R11 POST-MORTEM: spill fixed (k_swp <41us) but total only 182->173us;
// launch count + dispatch footprint is the lever, not per-kernel compute.
// R12/R13 POST-MORTEM (240.7us): device-scope fp32 atomicAdd -> memory-side
// line RMW (WRITE_SIZE 65.5MB for 512KB output), ~25ns each. Never atomic-
// reduce MB-scale data cross-XCD.
// R14 POST-MORTEM (198.5us, +25 vs R10): e-flow works but k_pool at 32 blocks
// left 87% of CUs idle pulling cold x -> est 25-40us. Top-5 = 268MB poison
// fills @41us: L3 fully evicted per iteration; per-iteration fill floor
// ~120us is harness-fixed.
// R17: widen k_pool 32 -> 128 blocks, still owner-computes. Grid (8 b, 16 dc):
// block owns 64-d chunk, loops all 1024 s. 16 waves = (head-group hg,
// row-quarter rq); lane = (row-sub, 16 d-lanes); acc = 4 float4/lane (16
// VGPR). Cross row-sub: shfl_xor(16,32); cross-rq: LDS (reuses e-staging
// buffer). No slabs, no atomics, no extra launch.
// R18-R20 (this round): benches never ran (GPU acquisition timeouts) ->
// resubmit R17 UNCHANGED; the widened-pool hypothesis must be measured
// before stacking anything else.

#define DIM  1024
#define NH   16
#define HD   64
#define BS   8
#define SEQ  1024
#define NNB  50

// workspace offsets (floats), all 16B-aligned
#define OF_P     16        // p:    128*1024
#define OF_E     131088    // e:    8*1024*16
#define OF_DENP  262160    // denp: 32*8*16
#define OF_XW    266256    // xw:   128*1024 (pre-normalized pool)
#define OF_CTX   397328    // ctx:  8*1024
#define OF_OUTR  405520    // outr: 8*1024

// ---------------- K1: fused neighbor-pool + q + p, one block per (h,b) -------
__global__ void k_prep(const float* __restrict__ xnb, const float* __restrict__ nm,
                       const float* __restrict__ qw, const float* __restrict__ qb,
                       const float* __restrict__ kw, float* __restrict__ p){
  int h = blockIdx.x & 15, b = blockIdx.x >> 4;
  int tid = threadIdx.x, wv = tid >> 6, ln = tid & 63;
  __shared__ float xnl[1024];
  __shared__ float qp[256];
  __shared__ float ql[64];
  {  // masked neighbor mean
    int d = tid*4;
    float4 acc = {0,0,0,0}; float wsum = 0.f;
    #pragma unroll 10
    for (int n=0; n<NNB; n++){
      float w = nm[b*NNB + n];
      float4 v = *(const float4*)(xnb + (size_t)(b*NNB + n)*DIM + d);
      acc.x += w*v.x; acc.y += w*v.y; acc.z += w*v.z; acc.w += w*v.w;
      wsum += w;
    }
    float inv = 1.f/wsum;
    acc.x*=inv; acc.y*=inv; acc.z*=inv; acc.w*=inv;
    *(float4*)(xnl + d) = acc;
  }
  __syncthreads();
  {  // q partial: lane ln -> row h*64+ln of qw, wave wv -> 256-d chunk
    const float* qrow = qw + (size_t)(h*HD + ln)*DIM + wv*256;
    const float* xrow = xnl + wv*256;
    float part = 0.f;
    #pragma unroll 16
    for (int i=0; i<64; i++){
      float4 a = *(const float4*)(qrow + i*4);
      float4 c = *(const float4*)(xrow + i*4);
      part += a.x*c.x + a.y*c.y + a.z*c.z + a.w*c.w;
    }
    qp[wv*64 + ln] = part;
  }
  __syncthreads();
  if (wv == 0){
    float qv = qp[ln] + qp[64+ln] + qp[128+ln] + qp[192+ln];
    ql[ln] = (qv + qb[h*HD + ln]) * 0.125f;
  }
  __syncthreads();
  {  // p[b,h,d] = sum_j ql[j]*kw[h*64+j,d]
    int d = tid*4;
    float4 acc = {0,0,0,0};
    #pragma unroll 8
    for (int j=0; j<HD; j++){
      float qj = ql[j];
      float4 kv = *(const float4*)(kw + (size_t)(h*HD + j)*DIM + d);
      acc.x += qj*kv.x; acc.y += qj*kv.y; acc.z += qj*kv.z; acc.w += qj*kv.w;
    }
    *(float4*)(p + (size_t)(b*NH + h)*DIM + d) = acc;
  }
}

// ---------------- K2: scores + exp -> e, denp (phases A+B only) -------------
// grid (8 b, 32 sc), block 1024 = 16 waves. Block: 32 seq rows x 16 heads.
// Phase A: wave wv -> (hg = wv&3 head-group, sq = wv>>2 s-quarter of 8 rows).
//   p for 4 heads in registers; x direct from global (L1/L2-hot across the
//   4 hg-waves); shfl_xor butterfly completes the 1024-d dot.
// Phase B: 512 threads compute e = mask*exp(score), write to global e
//   (contiguous 2 KB) and wf; den partial per head -> denp slab (no atomics).
__global__ __launch_bounds__(1024, 4)
void k_swp(const float* __restrict__ x, const float* __restrict__ p,
           const int* __restrict__ mask,
           float* __restrict__ e, float* __restrict__ denp){
  int b = blockIdx.x, sc = blockIdx.y;
  int s0 = sc * 32;
  int tid = threadIdx.x, wv = tid >> 6, ln = tid & 63;
  __shared__ float wf[32*20];          // [s][h] stride-20, 2.5 KB

  int hg = wv & 3, sq = wv >> 2;
  float acc[8][4];
  #pragma unroll
  for (int i=0; i<8; i++){ acc[i][0]=0.f; acc[i][1]=0.f; acc[i][2]=0.f; acc[i][3]=0.f; }

  #pragma unroll 1
  for (int kc=0; kc<4; kc++){
    int d = kc*256 + ln*4;
    const float* pb = p + (size_t)(b*NH + hg*4)*DIM + d;
    float4 pr0 = *(const float4*)(pb);
    float4 pr1 = *(const float4*)(pb +   (size_t)DIM);
    float4 pr2 = *(const float4*)(pb + 2*(size_t)DIM);
    float4 pr3 = *(const float4*)(pb + 3*(size_t)DIM);
    const float* xb = x + (size_t)(b*SEQ + s0 + sq*8)*DIM + d;
    #pragma unroll
    for (int sb=0; sb<8; sb+=4){
      float4 xr[4];
      #pragma unroll
      for (int u=0; u<4; u++)
        xr[u] = *(const float4*)(xb + (size_t)(sb+u)*DIM);
      #pragma unroll
      for (int u=0; u<4; u++){
        acc[sb+u][0] += xr[u].x*pr0.x + xr[u].y*pr0.y + xr[u].z*pr0.z + xr[u].w*pr0.w;
        acc[sb+u][1] += xr[u].x*pr1.x + xr[u].y*pr1.y + xr[u].z*pr1.z + xr[u].w*pr1.w;
        acc[sb+u][2] += xr[u].x*pr2.x + xr[u].y*pr2.y + xr[u].z*pr2.z + xr[u].w*pr2.w;
        acc[sb+u][3] += xr[u].x*pr3.x + xr[u].y*pr3.y + xr[u].z*pr3.z + xr[u].w*pr3.w;
      }
    }
  }
  // butterfly: complete each (s,h) dot across the 64 lanes' d-slices
  #pragma unroll
  for (int off=1; off<64; off<<=1){
    #pragma unroll
    for (int si=0; si<8; si++){
      acc[si][0] += __shfl_xor(acc[si][0], off, 64);
      acc[si][1] += __shfl_xor(acc[si][1], off, 64);
      acc[si][2] += __shfl_xor(acc[si][2], off, 64);
      acc[si][3] += __shfl_xor(acc[si][3], off, 64);
    }
  }
  if (ln == 0){
    #pragma unroll
    for (int si=0; si<8; si++){
      float4 v; v.x = acc[si][0]; v.y = acc[si][1]; v.z = acc[si][2]; v.w = acc[si][3];
      *(float4*)(wf + (sq*8 + si)*20 + hg*4) = v;
    }
  }
  __syncthreads();
  if (tid < 512){                      // phase B: e = mask * exp(score)
    int s = tid >> 4, h = tid & 15;
    float sv = wf[s*20 + h];
    float ev = mask[b*SEQ + s0 + s] ? __expf(sv) : 0.f;
    wf[s*20 + h] = ev;
    e[(size_t)(b*SEQ + s0)*NH + tid] = ev;   // [b][s][h], contiguous 2 KB
  }
  __syncthreads();
  if (tid < 16){                       // den partial per head -> slab
    float dsum = 0.f;
    #pragma unroll
    for (int ss=0; ss<32; ss++) dsum += wf[ss*20 + tid];
    denp[(sc*BS + b)*NH + tid] = dsum;
  }
}

// ---------------- K3: owner-computes weighted pool (v2: 128 blocks) ---------
// grid (8 b, 16 dc), block 1024 = 16 waves. Block owns 64-d chunk, loops all
// 1024 s. Wave wv = (hg = wv&3 head-group, rq = wv>>2 row-quarter of 256).
// Lane = (rs = ln>>4 row-sub, 16 d-lanes); acc = 4 float4 (16 VGPR).
// Cross row-sub: shfl_xor(16,32). Cross-rq: LDS (reuses e buffer).
// 1/den folded; xw written pre-normalized. No slabs, no atomics.
__global__ __launch_bounds__(1024, 4)
void k_pool(const float* __restrict__ x, const float* __restrict__ e,
            const float* __restrict__ denp, float* __restrict__ xw){
  int b = blockIdx.x, dc = blockIdx.y;
  int tid = threadIdx.x, wv = tid >> 6, ln = tid & 63;
  int hg = wv & 3, rq = wv >> 2;
  __shared__ float elds[SEQ*NH];       // 64 KB: e[b] as [s][h]; reused as redbuf
  __shared__ float invd[NH];
  const float* eb = e + (size_t)b*SEQ*NH;
  #pragma unroll
  for (int it=0; it<4; it++){          // stage e: 16384 floats via float4
    int idx = it*4096 + tid*4;
    *(float4*)(elds + idx) = *(const float4*)(eb + idx);
  }
  if (tid < NH){                       // den = sum of 32 slab partials
    float dsum = 0.f;
    #pragma unroll
    for (int sc=0; sc<32; sc++) dsum += denp[(sc*BS + b)*NH + tid];
    invd[tid] = 1.f/dsum;
  }
  __syncthreads();
  int rs = ln >> 4;                    // row-sub 0..3
  int d  = dc*64 + (ln & 15)*4;        // owned d (4 floats)
  float4 a0={0,0,0,0}, a1={0,0,0,0}, a2={0,0,0,0}, a3={0,0,0,0};
  int sbase = rq*256 + rs;
  const float* xb = x + (size_t)(b*SEQ + sbase)*DIM + d;
  const float* el = elds + (size_t)sbase*NH + hg*4;
  #pragma unroll 1
  for (int it=0; it<64; it+=4){        // rows sbase + {it..it+3}*4
    float4 xq[4];
    #pragma unroll
    for (int u=0; u<4; u++)
      xq[u] = *(const float4*)(xb + (size_t)(it+u)*4*DIM);   // 4 loads in flight
    #pragma unroll
    for (int u=0; u<4; u++){
      float4 w = *(const float4*)(el + (size_t)(it+u)*4*NH);
      a0.x += xq[u].x*w.x; a0.y += xq[u].y*w.x; a0.z += xq[u].z*w.x; a0.w += xq[u].w*w.x;
      a1.x += xq[u].x*w.y; a1.y += xq[u].y*w.y; a1.z += xq[u].z*w.y; a1.w += xq[u].w*w.y;
      a2.x += xq[u].x*w.z; a2.y += xq[u].y*w.z; a2.z += xq[u].z*w.z; a2.w += xq[u].w*w.z;
      a3.x += xq[u].x*w.w; a3.y += xq[u].y*w.w; a3.z += xq[u].z*w.w; a3.w += xq[u].w*w.w;
    }
  }
  // cross row-sub reduce: lanes c, c+16, c+32, c+48 hold the same d
  #pragma unroll
  for (int off=16; off<=32; off<<=1){
    a0.x += __shfl_xor(a0.x, off, 64); a0.y += __shfl_xor(a0.y, off, 64);
    a0.z += __shfl_xor(a0.z, off, 64); a0.w += __shfl_xor(a0.w, off, 64);
    a1.x += __shfl_xor(a1.x, off, 64); a1.y += __shfl_xor(a1.y, off, 64);
    a1.z += __shfl_xor(a1.z, off, 64); a1.w += __shfl_xor(a1.w, off, 64);
    a2.x += __shfl_xor(a2.x, off, 64); a2.y += __shfl_xor(a2.y, off, 64);
    a2.z += __shfl_xor(a2.z, off, 64); a2.w += __shfl_xor(a2.w, off, 64);
    a3.x += __shfl_xor(a3.x, off, 64); a3.y += __shfl_xor(a3.y, off, 64);
    a3.z += __shfl_xor(a3.z, off, 64); a3.w += __shfl_xor(a3.w, off, 64);
  }
  __syncthreads();                     // e reads done; reuse elds as redbuf
  float4* red = (float4*)elds;         // red[q*1024 + wv*16 + lane<16]
  if (ln < 16){
    red[0*1024 + wv*16 + ln] = a0;
    red[1*1024 + wv*16 + ln] = a1;
    red[2*1024 + wv*16 + ln] = a2;
    red[3*1024 + wv*16 + ln] = a3;
  }
  __syncthreads();
  if (rq == 0 && ln < 16){             // waves 0..3 (one per hg) finalize
    #pragma unroll
    for (int q=0; q<4; q++){
      float4 s = red[q*1024 + (0*4 + hg)*16 + ln];
      #pragma unroll
      for (int r=1; r<4; r++){
        float4 t = red[q*1024 + (r*4 + hg)*16 + ln];
        s.x += t.x; s.y += t.y; s.z += t.z; s.w += t.w;
      }
      float iv = invd[hg*4 + q];
      s.x *= iv; s.y *= iv; s.z *= iv; s.w *= iv;
      *(float4*)(xw + (size_t)(b*NH + hg*4 + q)*DIM + d) = s;
    }
  }
}

// ---------------- K4: ctx[b,jo] = xw[b,h(jo),:].vw[jo,:] + vb[jo] ----------
__global__ void k_ctx(const float* __restrict__ xw, const float* __restrict__ vw,
                      const float* __restrict__ vb, float* __restrict__ ctx){
  int wv = threadIdx.x >> 6, ln = threadIdx.x & 63;
  int jo = blockIdx.x*4 + wv;
  int h  = jo >> 6;
  float acc[BS] = {0,0,0,0,0,0,0,0};
  #pragma unroll
  for (int i=0; i<4; i++){
    int d = ln*4 + 256*i;
    float4 vv = *(const float4*)(vw + (size_t)jo*DIM + d);
    #pragma unroll
    for (int b=0; b<BS; b++){
      float4 xv = *(const float4*)(xw + (size_t)(b*NH + h)*DIM + d);
      acc[b] += vv.x*xv.x + vv.y*xv.y + vv.z*xv.z + vv.w*xv.w;
    }
  }
  #pragma unroll
  for (int off=32; off>=1; off>>=1){
    #pragma unroll
    for (int b=0; b<BS; b++) acc[b] += __shfl_down(acc[b], off, 64);
  }
  if (ln == 0){
    float bias = vb[jo];
    #pragma unroll
    for (int b=0; b<BS; b++) ctx[b*DIM + jo] = acc[b] + bias;
  }
}

// ---------------- K5: out_row[b,i] = ctx[b,:].ow[i,:] + ob[i] ----------------
__global__ void k_outrow(const float* __restrict__ ctx, const float* __restrict__ ow,
                         const float* __restrict__ ob, float* __restrict__ outr){
  int wv = threadIdx.x >> 6, ln = threadIdx.x & 63;
  int io = blockIdx.x*4 + wv;
  float acc[BS] = {0,0,0,0,0,0,0,0};
  #pragma unroll
  for (int i=0; i<4; i++){
    int d = ln*4 + 256*i;
    float4 wt = *(const float4*)(ow + (size_t)io*DIM + d);
    #pragma unroll
    for (int b=0; b<BS; b++){
      float4 cv = *(const float4*)(ctx + b*DIM + d);
      acc[b] += wt.x*cv.x + wt.y*cv.y + wt.z*cv.z + wt.w*cv.w;
    }
  }
  #pragma unroll
  for (int off=32; off>=1; off>>=1){
    #pragma unroll
    for (int b=0; b<BS; b++) acc[b] += __shfl_down(acc[b], off, 64);
  }
  if (ln == 0){
    float bias = ob[io];
    #pragma unroll
    for (int b=0; b<BS; b++) outr[b*DIM + io] = acc[b] + bias;
  }
}

// ---------------- K6: out[b,s,:] = LN(out_row[b]+x[b,s,:])*g + beta ---------
__global__ void k_ln(const float* __restrict__ x, const float* __restrict__ outr,
                     const float* __restrict__ g, const float* __restrict__ bt,
                     float* __restrict__ out){
  int row = blockIdx.x;
  int b = row >> 10;
  size_t base = (size_t)row * DIM;
  int tid = threadIdx.x;
  float4 xv = ((const float4*)(x + base))[tid];
  float4 ov = ((const float4*)(outr + (size_t)b*DIM))[tid];
  float4 h;
  h.x = xv.x + ov.x; h.y = xv.y + ov.y; h.z = xv.z + ov.z; h.w = xv.w + ov.w;
  float s  = h.x + h.y + h.z + h.w;
  float s2 = h.x*h.x + h.y*h.y + h.z*h.z + h.w*h.w;
  #pragma unroll
  for (int off=32; off>=1; off>>=1){
    s  += __shfl_xor(s,  off, 64);
    s2 += __shfl_xor(s2, off, 64);
  }
  __shared__ float r1[4], r2[4];
  int wv = tid >> 6, ln = tid & 63;
  if (ln == 0){ r1[wv] = s; r2[wv] = s2; }
  __syncthreads();
  s  = r1[0] + r1[1] + r1[2] + r1[3];
  s2 = r2[0] + r2[1] + r2[2] + r2[3];
  float mu   = s  * (1.f/1024.f);
  float var  = s2 * (1.f/1024.f) - mu*mu;
  float rstd = rsqrtf(var + 1e-12f);
  float4 gv = ((const float4*)g)[tid];
  float4 bv = ((const float4*)bt)[tid];
  float4 y;
  y.x = (h.x - mu)*rstd*gv.x + bv.x;
  y.y = (h.y - mu)*rstd*gv.y + bv.y;
  y.z = (h.z - mu)*rstd*gv.z + bv.z;
  y.w = (h.w - mu)*rstd*gv.w + bv.w;
  ((float4*)(out + base))[tid] = y;
}

extern "C" void kernel_launch(void* const* d_in, const int* in_sizes, int n_in,
                              void* d_out, int out_size, void* d_ws, size_t ws_size,
                              hipStream_t stream) {
  const float* x    = (const float*)d_in[0];
  const float* xnb  = (const float*)d_in[1];
  const int*   mask = (const int*  )d_in[2];
  const float* nm   = (const float*)d_in[3];
  const float* qw   = (const float*)d_in[4];
  const float* qb   = (const float*)d_in[5];
  const float* kw   = (const float*)d_in[6];
  // d_in[7] = kb: softmax-invariant constant, unused
  const float* vw   = (const float*)d_in[8];
  const float* vb   = (const float*)d_in[9];
  const float* ow   = (const float*)d_in[10];
  const float* ob   = (const float*)d_in[11];
  const float* lng  = (const float*)d_in[12];
  const float* lnb  = (const float*)d_in[13];
  float* out = (float*)d_out;

  float* ws   = (float*)d_ws;              // ~1.6 MB of ~256 MB ws
  float* p    = ws + OF_P;
  float* e    = ws + OF_E;                 // exp-weights, 512 KB
  float* denp = ws + OF_DENP;              // 32 x 128 den partials
  float* xw   = ws + OF_XW;                // pre-normalized pool
  float* ctx  = ws + OF_CTX;
  float* outr = ws + OF_OUTR;

  k_prep  <<<128,             256,  0, stream>>>(xnb, nm, qw, qb, kw, p);
  k_swp   <<<dim3(BS,32),     1024, 0, stream>>>(x, p, mask, e, denp);
  k_pool  <<<dim3(BS,16),     1024, 0, stream>>>(x, e, denp, xw);
  k_ctx   <<<256,             256,  0, stream>>>(xw, vw, vb, ctx);
  k_outrow<<<256,             256,  0, stream>>>(ctx, ow, ob, outr);
  k_ln    <<<BS*SEQ,          256,  0, stream>>>(x, outr, lng, lnb, out);
}

// Round 14
// 173.694 us; speedup vs baseline: 1.3859x; 1.0282x over previous
//
#include <hip/hip_runtime.h>
#include <hip/hip_bf16.h>

// NeighborAttention on MI355X. fp32 in/out, int32 mask.
// KEY INSIGHT (R0): query = broadcast of masked neighbor-mean -> all seq
// positions share one query per (b,h). Attention collapses to GEMV-scale work.
// R6/R7 POST-MORTEM: device-wide software barriers cost ~40us EACH on MI355X.
// R9 POST-MORTEM: fused k_swp @256 threads spilled -> 142.8us, VALUBusy 0.19%.
//   Also: 182 - 142.8 = 39us for the OTHER 5 kernels + gaps -> tail kernels
//   and launch gaps are cheap; k_swp-class kernels are the only big items.
// R10/R11 POST-MORTEM (measured 173.1): spill fixed, all kernels <41us.
// R12/R13 POST-MORTEM (240.7): device-scope fp32 atomicAdd = memory-side line
//   RMW (~25ns each, WRITE_SIZE 65.5MB for 512KB output). Never atomic-reduce
//   MB-scale data cross-XCD.
// R14 POST-MORTEM (198.5): e-flow + 32-block k_pool starved 87% of CUs.
// R17 POST-MORTEM (178.6): widened k_pool recovered R14 (-20us) but did not
//   beat R10. SESSION RECORD: 7-launch/scp=168.3, 6-launch/nump=173.1,
//   6-launch/e-flow=178.6 -- three structures within +-3%, improvements
//   trending slightly worse. Launch count and inter-stage traffic are minor
//   terms; ~100us of dur_us is overhead invisible to the dispatch table.
// R21: CONSOLIDATION. Revert to the best-measured variant (R10 design,
//   173.1us, byte-identical) and calibrate measurement noise with n=2 on
//   identical code. Within +-2 of 173 -> R17's delta was real, micro-opts
//   justified. Spread >=+-6 -> recent deltas were noise; session concludes
//   at the overhead floor with this kernel.
// R22 (this round): R21 bench never ran (GPU acquisition timeout) ->
//   resubmit UNCHANGED; the noise-calibration measurement must happen
//   before any further decision.

#define DIM  1024
#define NH   16
#define HD   64
#define BS   8
#define SEQ  1024
#define NNB  50

// workspace offsets (floats), all 16B-aligned
#define OF_P     16
#define OF_NUMP  131088
#define OF_DENP  4325392
#define OF_XW    4329488
#define OF_CTX   4460560
#define OF_OUTR  4468752

// ---------------- K1: fused neighbor-pool + q + p, one block per (h,b) -------
__global__ void k_prep(const float* __restrict__ xnb, const float* __restrict__ nm,
                       const float* __restrict__ qw, const float* __restrict__ qb,
                       const float* __restrict__ kw, float* __restrict__ p){
  int h = blockIdx.x & 15, b = blockIdx.x >> 4;
  int tid = threadIdx.x, wv = tid >> 6, ln = tid & 63;
  __shared__ float xnl[1024];
  __shared__ float qp[256];
  __shared__ float ql[64];
  {  // masked neighbor mean
    int d = tid*4;
    float4 acc = {0,0,0,0}; float wsum = 0.f;
    #pragma unroll 10
    for (int n=0; n<NNB; n++){
      float w = nm[b*NNB + n];
      float4 v = *(const float4*)(xnb + (size_t)(b*NNB + n)*DIM + d);
      acc.x += w*v.x; acc.y += w*v.y; acc.z += w*v.z; acc.w += w*v.w;
      wsum += w;
    }
    float inv = 1.f/wsum;
    acc.x*=inv; acc.y*=inv; acc.z*=inv; acc.w*=inv;
    *(float4*)(xnl + d) = acc;
  }
  __syncthreads();
  {  // q partial: lane ln -> row h*64+ln of qw, wave wv -> 256-d chunk
    const float* qrow = qw + (size_t)(h*HD + ln)*DIM + wv*256;
    const float* xrow = xnl + wv*256;
    float part = 0.f;
    #pragma unroll 16
    for (int i=0; i<64; i++){
      float4 a = *(const float4*)(qrow + i*4);
      float4 c = *(const float4*)(xrow + i*4);
      part += a.x*c.x + a.y*c.y + a.z*c.z + a.w*c.w;
    }
    qp[wv*64 + ln] = part;
  }
  __syncthreads();
  if (wv == 0){
    float qv = qp[ln] + qp[64+ln] + qp[128+ln] + qp[192+ln];
    ql[ln] = (qv + qb[h*HD + ln]) * 0.125f;
  }
  __syncthreads();
  {  // p[b,h,d] = sum_j ql[j]*kw[h*64+j,d]
    int d = tid*4;
    float4 acc = {0,0,0,0};
    #pragma unroll 8
    for (int j=0; j<HD; j++){
      float qj = ql[j];
      float4 kv = *(const float4*)(kw + (size_t)(h*HD + j)*DIM + d);
      acc.x += qj*kv.x; acc.y += qj*kv.y; acc.z += qj*kv.z; acc.w += qj*kv.w;
    }
    *(float4*)(p + (size_t)(b*NH + h)*DIM + d) = acc;
  }
}

// ---------------- K2: fused scores + exp + weighted pool (v2) ---------------
// grid (8 b, 32 sc), block 1024 = 16 waves. Block: 32 seq rows, 16 heads.
// Phase A: wave wv -> (hg = wv&3 head-group, sq = wv>>2 s-quarter of 8 rows).
//   Lane ln covers d = kc*256 + ln*4. p for 4 heads in registers (4 float4),
//   x read direct from global (1 KB contiguous per row per wave; 4 hg-waves
//   share rows -> L1-hot). acc[8][4] partials; shfl_xor butterfly over 64
//   lanes completes the 1024-d dot; lane 0 writes raw scores to wf.
// Phase B: 512 threads apply mask*exp in-place; den partial per head.
// Phase C: wave wv -> (hg2 = wv>>2, dc = wv&3); lane d = dc*256+ln*4; 4-head
//   float4 accumulators; x re-read (L1/L2-hot); writes nump slab sc.
__global__ __launch_bounds__(1024, 4)
void k_swp(const float* __restrict__ x, const float* __restrict__ p,
           const int* __restrict__ mask,
           float* __restrict__ nump, float* __restrict__ denp){
  int b = blockIdx.x, sc = blockIdx.y;
  int s0 = sc * 32;
  int tid = threadIdx.x, wv = tid >> 6, ln = tid & 63;
  __shared__ float wf[32*20];          // [s][h] stride-20, 2.5 KB

  int hg = wv & 3, sq = wv >> 2;
  float acc[8][4];
  #pragma unroll
  for (int i=0; i<8; i++){ acc[i][0]=0.f; acc[i][1]=0.f; acc[i][2]=0.f; acc[i][3]=0.f; }

  #pragma unroll 1
  for (int kc=0; kc<4; kc++){
    int d = kc*256 + ln*4;
    const float* pb = p + (size_t)(b*NH + hg*4)*DIM + d;
    float4 pr0 = *(const float4*)(pb);
    float4 pr1 = *(const float4*)(pb +   (size_t)DIM);
    float4 pr2 = *(const float4*)(pb + 2*(size_t)DIM);
    float4 pr3 = *(const float4*)(pb + 3*(size_t)DIM);
    const float* xb = x + (size_t)(b*SEQ + s0 + sq*8)*DIM + d;
    #pragma unroll
    for (int sb=0; sb<8; sb+=4){
      float4 xr[4];
      #pragma unroll
      for (int u=0; u<4; u++)
        xr[u] = *(const float4*)(xb + (size_t)(sb+u)*DIM);
      #pragma unroll
      for (int u=0; u<4; u++){
        acc[sb+u][0] += xr[u].x*pr0.x + xr[u].y*pr0.y + xr[u].z*pr0.z + xr[u].w*pr0.w;
        acc[sb+u][1] += xr[u].x*pr1.x + xr[u].y*pr1.y + xr[u].z*pr1.z + xr[u].w*pr1.w;
        acc[sb+u][2] += xr[u].x*pr2.x + xr[u].y*pr2.y + xr[u].z*pr2.z + xr[u].w*pr2.w;
        acc[sb+u][3] += xr[u].x*pr3.x + xr[u].y*pr3.y + xr[u].z*pr3.z + xr[u].w*pr3.w;
      }
    }
  }
  // butterfly: complete each (s,h) dot across the 64 lanes' d-slices
  #pragma unroll
  for (int off=1; off<64; off<<=1){
    #pragma unroll
    for (int si=0; si<8; si++){
      acc[si][0] += __shfl_xor(acc[si][0], off, 64);
      acc[si][1] += __shfl_xor(acc[si][1], off, 64);
      acc[si][2] += __shfl_xor(acc[si][2], off, 64);
      acc[si][3] += __shfl_xor(acc[si][3], off, 64);
    }
  }
  if (ln == 0){
    #pragma unroll
    for (int si=0; si<8; si++){
      float4 v; v.x = acc[si][0]; v.y = acc[si][1]; v.z = acc[si][2]; v.w = acc[si][3];
      *(float4*)(wf + (sq*8 + si)*20 + hg*4) = v;
    }
  }
  __syncthreads();
  if (tid < 512){                      // phase B: e = mask * exp(score), in place
    int s = tid >> 4, h = tid & 15;
    float sv = wf[s*20 + h];
    wf[s*20 + h] = mask[b*SEQ + s0 + s] ? __expf(sv) : 0.f;
  }
  __syncthreads();
  if (tid < 16){                       // den partial per head (once per (b,sc))
    float dsum = 0.f;
    #pragma unroll
    for (int ss=0; ss<32; ss++) dsum += wf[ss*20 + tid];
    denp[(sc*BS + b)*NH + tid] = dsum;
  }
  // phase C: weighted pool. wave wv -> heads hg2*4..+3, d chunk dc*256..+255.
  int hg2 = wv >> 2, dc = wv & 3;
  int d = dc*256 + ln*4;
  const float* xbase = x + (size_t)(b*SEQ + s0)*DIM + d;
  float4 a0={0,0,0,0}, a1={0,0,0,0}, a2={0,0,0,0}, a3={0,0,0,0};
  #pragma unroll 2
  for (int sb=0; sb<32; sb+=4){
    float4 xq[4];
    #pragma unroll
    for (int u=0; u<4; u++)
      xq[u] = *(const float4*)(xbase + (size_t)(sb+u)*DIM);
    #pragma unroll
    for (int u=0; u<4; u++){
      float4 w = *(const float4*)(wf + (sb+u)*20 + hg2*4);   // wave-uniform bcast
      a0.x += xq[u].x*w.x; a0.y += xq[u].y*w.x; a0.z += xq[u].z*w.x; a0.w += xq[u].w*w.x;
      a1.x += xq[u].x*w.y; a1.y += xq[u].y*w.y; a1.z += xq[u].z*w.y; a1.w += xq[u].w*w.y;
      a2.x += xq[u].x*w.z; a2.y += xq[u].y*w.z; a2.z += xq[u].z*w.z; a2.w += xq[u].w*w.z;
      a3.x += xq[u].x*w.w; a3.y += xq[u].y*w.w; a3.z += xq[u].z*w.w; a3.w += xq[u].w*w.w;
    }
  }
  float* dst = nump + (size_t)sc*(BS*NH*DIM) + (size_t)(b*NH + hg2*4)*DIM + d;
  *(float4*)(dst                 ) = a0;
  *(float4*)(dst +   (size_t)DIM ) = a1;
  *(float4*)(dst + 2*(size_t)DIM ) = a2;
  *(float4*)(dst + 3*(size_t)DIM ) = a3;
}

// ---------------- K3: xw[b,h,d] = sum_sc num / sum_sc den ------------------
__global__ void k_xwred(const float* __restrict__ nump, const float* __restrict__ denp,
                        float* __restrict__ xw){
  int id = blockIdx.x*256 + threadIdx.x;   // 512 blocks -> 131072 ids
  int bh = id >> 10;                        // b*NH + h
  int b = bh >> 4, h = bh & 15;
  float den = 0.f;
  #pragma unroll
  for (int scn=0; scn<32; scn++) den += denp[(scn*BS + b)*NH + h];
  float num = 0.f;
  #pragma unroll
  for (int scn=0; scn<32; scn++) num += nump[(size_t)scn*(BS*NH*DIM) + id];
  xw[id] = num / den;
}

// ---------------- K4: ctx[b,jo] = xw[b,h(jo),:].vw[jo,:] + vb[jo] ----------
__global__ void k_ctx(const float* __restrict__ xw, const float* __restrict__ vw,
                      const float* __restrict__ vb, float* __restrict__ ctx){
  int wv = threadIdx.x >> 6, ln = threadIdx.x & 63;
  int jo = blockIdx.x*4 + wv;
  int h  = jo >> 6;
  float acc[BS] = {0,0,0,0,0,0,0,0};
  #pragma unroll
  for (int i=0; i<4; i++){
    int d = ln*4 + 256*i;
    float4 vv = *(const float4*)(vw + (size_t)jo*DIM + d);
    #pragma unroll
    for (int b=0; b<BS; b++){
      float4 xv = *(const float4*)(xw + (size_t)(b*NH + h)*DIM + d);
      acc[b] += vv.x*xv.x + vv.y*xv.y + vv.z*xv.z + vv.w*xv.w;
    }
  }
  #pragma unroll
  for (int off=32; off>=1; off>>=1){
    #pragma unroll
    for (int b=0; b<BS; b++) acc[b] += __shfl_down(acc[b], off, 64);
  }
  if (ln == 0){
    float bias = vb[jo];
    #pragma unroll
    for (int b=0; b<BS; b++) ctx[b*DIM + jo] = acc[b] + bias;
  }
}

// ---------------- K5: out_row[b,i] = ctx[b,:].ow[i,:] + ob[i] ----------------
__global__ void k_outrow(const float* __restrict__ ctx, const float* __restrict__ ow,
                         const float* __restrict__ ob, float* __restrict__ outr){
  int wv = threadIdx.x >> 6, ln = threadIdx.x & 63;
  int io = blockIdx.x*4 + wv;
  float acc[BS] = {0,0,0,0,0,0,0,0};
  #pragma unroll
  for (int i=0; i<4; i++){
    int d = ln*4 + 256*i;
    float4 wt = *(const float4*)(ow + (size_t)io*DIM + d);
    #pragma unroll
    for (int b=0; b<BS; b++){
      float4 cv = *(const float4*)(ctx + b*DIM + d);
      acc[b] += wt.x*cv.x + wt.y*cv.y + wt.z*cv.z + wt.w*cv.w;
    }
  }
  #pragma unroll
  for (int off=32; off>=1; off>>=1){
    #pragma unroll
    for (int b=0; b<BS; b++) acc[b] += __shfl_down(acc[b], off, 64);
  }
  if (ln == 0){
    float bias = ob[io];
    #pragma unroll
    for (int b=0; b<BS; b++) outr[b*DIM + io] = acc[b] + bias;
  }
}

// ---------------- K6: out[b,s,:] = LN(out_row[b]+x[b,s,:])*g + beta ---------
__global__ void k_ln(const float* __restrict__ x, const float* __restrict__ outr,
                     const float* __restrict__ g, const float* __restrict__ bt,
                     float* __restrict__ out){
  int row = blockIdx.x;
  int b = row >> 10;
  size_t base = (size_t)row * DIM;
  int tid = threadIdx.x;
  float4 xv = ((const float4*)(x + base))[tid];
  float4 ov = ((const float4*)(outr + (size_t)b*DIM))[tid];
  float4 h;
  h.x = xv.x + ov.x; h.y = xv.y + ov.y; h.z = xv.z + ov.z; h.w = xv.w + ov.w;
  float s  = h.x + h.y + h.z + h.w;
  float s2 = h.x*h.x + h.y*h.y + h.z*h.z + h.w*h.w;
  #pragma unroll
  for (int off=32; off>=1; off>>=1){
    s  += __shfl_xor(s,  off, 64);
    s2 += __shfl_xor(s2, off, 64);
  }
  __shared__ float r1[4], r2[4];
  int wv = tid >> 6, ln = tid & 63;
  if (ln == 0){ r1[wv] = s; r2[wv] = s2; }
  __syncthreads();
  s  = r1[0] + r1[1] + r1[2] + r1[3];
  s2 = r2[0] + r2[1] + r2[2] + r2[3];
  float mu   = s  * (1.f/1024.f);
  float var  = s2 * (1.f/1024.f) - mu*mu;
  float rstd = rsqrtf(var + 1e-12f);
  float4 gv = ((const float4*)g)[tid];
  float4 bv = ((const float4*)bt)[tid];
  float4 y;
  y.x = (h.x - mu)*rstd*gv.x + bv.x;
  y.y = (h.y - mu)*rstd*gv.y + bv.y;
  y.z = (h.z - mu)*rstd*gv.z + bv.z;
  y.w = (h.w - mu)*rstd*gv.w + bv.w;
  ((float4*)(out + base))[tid] = y;
}

extern "C" void kernel_launch(void* const* d_in, const int* in_sizes, int n_in,
                              void* d_out, int out_size, void* d_ws, size_t ws_size,
                              hipStream_t stream) {
  const float* x    = (const float*)d_in[0];
  const float* xnb  = (const float*)d_in[1];
  const int*   mask = (const int*  )d_in[2];
  const float* nm   = (const float*)d_in[3];
  const float* qw   = (const float*)d_in[4];
  const float* qb   = (const float*)d_in[5];
  const float* kw   = (const float*)d_in[6];
  // d_in[7] = kb: softmax-invariant constant, unused
  const float* vw   = (const float*)d_in[8];
  const float* vb   = (const float*)d_in[9];
  const float* ow   = (const float*)d_in[10];
  const float* ob   = (const float*)d_in[11];
  const float* lng  = (const float*)d_in[12];
  const float* lnb  = (const float*)d_in[13];
  float* out = (float*)d_out;

  float* ws   = (float*)d_ws;              // ~17.9 MB of ~256 MB ws
  float* p    = ws + OF_P;
  float* nump = ws + OF_NUMP;              // 32 s-chunk slabs
  float* denp = ws + OF_DENP;              // 32 x 128
  float* xw   = ws + OF_XW;
  float* ctx  = ws + OF_CTX;
  float* outr = ws + OF_OUTR;

  k_prep  <<<128,             256,  0, stream>>>(xnb, nm, qw, qb, kw, p);
  k_swp   <<<dim3(BS,32),     1024, 0, stream>>>(x, p, mask, nump, denp);
  k_xwred <<<512,             256,  0, stream>>>(nump, denp, xw);
  k_ctx   <<<256,             256,  0, stream>>>(xw, vw, vb, ctx);
  k_outrow<<<256,             256,  0, stream>>>(ctx, ow, ob, outr);
  k_ln    <<<BS*SEQ,          256,  0, stream>>>(x, outr, lng, lnb, out);
}

// Round 19
// 170.289 us; speedup vs baseline: 1.4137x; 1.0200x over previous
//
#include <hip/hip_runtime.h>
#include <hip/hip_bf16.h>

// NeighborAttention on MI355X. fp32 in/out, int32 mask.
// KEY INSIGHT (R0): query = broadcast of masked neighbor-mean -> all seq
// positions share one query per (b,h). Attention collapses to GEMV-scale work.
// R6/R7: device-wide software barriers cost ~40us EACH on MI355X.
// R9: fused k_swp @256 threads spilled -> 142.8us. Tail kernels+gaps ~39us.
// R10/R11 (173.1): spill fixed via 1024-thr blocks, all kernels <41us.
// R12/R13 (240.7): device-scope fp32 atomicAdd = memory-side line RMW
//   (~25ns each). Never atomic-reduce MB-scale data cross-XCD.
// R14 (198.5): e-flow + 32-block k_pool starved 87% of CUs.
// R17 (178.6): widened k_pool recovered R14 but did not beat R10.
// R21/R23 NOISE CALIBRATION (measured): identical code 173.1 vs 173.7 ->
//   noise ~ +-1us. R17's 178.6 was a REAL ~5us regression; R10 design is the
//   session's best. Top-5 = poison fills @41us x3+: ~120us of dur_us is
//   harness reset, only ~50-60us is kernel-addressable.
// R24: pre-registered k_swp micro-opt. (1) Phase A reduction: 6-level
//   butterfly (192 shfl_xor/wave, ds_bpermute on LDS pipe) replaced by
//   FOLDING reduction (keep half whose value-bit matches lane-bit):
//   16+8+4+2+1+1 = 32 shfls/wave, result v=ln&31 lands on lane ln.
//   (2) Phase C x-load pipeline 4 -> 8 in flight (fits: 16 acc + 32 xq VGPR).
//   Predict total 173.7 -> 169-172; if >=173, micro-opts are sub-threshold
//   and the session is at the overhead floor.
// R25-R28 (this round): R24 bench never ran (3x acquisition timeout, 1x
//   container bring-up failure -- all environment-side) -> resubmit
//   UNCHANGED. Folding reduction already re-verified algebraically
//   (level-k invariant + lane/value index mapping + no exec-mask hazard).

#define DIM  1024
#define NH   16
#define HD   64
#define BS   8
#define SEQ  1024
#define NNB  50

// workspace offsets (floats), all 16B-aligned
#define OF_P     16
#define OF_NUMP  131088
#define OF_DENP  4325392
#define OF_XW    4329488
#define OF_CTX   4460560
#define OF_OUTR  4468752

// ---------------- K1: fused neighbor-pool + q + p, one block per (h,b) -------
__global__ void k_prep(const float* __restrict__ xnb, const float* __restrict__ nm,
                       const float* __restrict__ qw, const float* __restrict__ qb,
                       const float* __restrict__ kw, float* __restrict__ p){
  int h = blockIdx.x & 15, b = blockIdx.x >> 4;
  int tid = threadIdx.x, wv = tid >> 6, ln = tid & 63;
  __shared__ float xnl[1024];
  __shared__ float qp[256];
  __shared__ float ql[64];
  {  // masked neighbor mean
    int d = tid*4;
    float4 acc = {0,0,0,0}; float wsum = 0.f;
    #pragma unroll 10
    for (int n=0; n<NNB; n++){
      float w = nm[b*NNB + n];
      float4 v = *(const float4*)(xnb + (size_t)(b*NNB + n)*DIM + d);
      acc.x += w*v.x; acc.y += w*v.y; acc.z += w*v.z; acc.w += w*v.w;
      wsum += w;
    }
    float inv = 1.f/wsum;
    acc.x*=inv; acc.y*=inv; acc.z*=inv; acc.w*=inv;
    *(float4*)(xnl + d) = acc;
  }
  __syncthreads();
  {  // q partial: lane ln -> row h*64+ln of qw, wave wv -> 256-d chunk
    const float* qrow = qw + (size_t)(h*HD + ln)*DIM + wv*256;
    const float* xrow = xnl + wv*256;
    float part = 0.f;
    #pragma unroll 16
    for (int i=0; i<64; i++){
      float4 a = *(const float4*)(qrow + i*4);
      float4 c = *(const float4*)(xrow + i*4);
      part += a.x*c.x + a.y*c.y + a.z*c.z + a.w*c.w;
    }
    qp[wv*64 + ln] = part;
  }
  __syncthreads();
  if (wv == 0){
    float qv = qp[ln] + qp[64+ln] + qp[128+ln] + qp[192+ln];
    ql[ln] = (qv + qb[h*HD + ln]) * 0.125f;
  }
  __syncthreads();
  {  // p[b,h,d] = sum_j ql[j]*kw[h*64+j,d]
    int d = tid*4;
    float4 acc = {0,0,0,0};
    #pragma unroll 8
    for (int j=0; j<HD; j++){
      float qj = ql[j];
      float4 kv = *(const float4*)(kw + (size_t)(h*HD + j)*DIM + d);
      acc.x += qj*kv.x; acc.y += qj*kv.y; acc.z += qj*kv.z; acc.w += qj*kv.w;
    }
    *(float4*)(p + (size_t)(b*NH + h)*DIM + d) = acc;
  }
}

// ---------------- K2: fused scores + exp + weighted pool (v3) ---------------
// grid (8 b, 32 sc), block 1024 = 16 waves. Block: 32 seq rows, 16 heads.
// Phase A: wave wv -> (hg = wv&3 head-group, sq = wv>>2 s-quarter of 8 rows).
//   Lane ln covers d = kc*256 + ln*4. p for 4 heads in registers; x direct
//   from global (4 hg-waves share rows -> L1-hot). acc[8][4] partials, then
//   FOLDING reduction (32 shfls/wave, not 192): level k keeps the half of
//   the value set whose bit k matches lane bit k; after 5 levels + one
//   cross-half add, lane ln holds value v = ln&31 (si = (ln>>2)&7, hj = ln&3)
//   fully summed over 64 lanes. Lanes <32 write wf.
// Phase B: 512 threads apply mask*exp in-place; den partial per head.
// Phase C: wave wv -> (hg2 = wv>>2, dc = wv&3); 8 x-loads in flight.
__global__ __launch_bounds__(1024, 4)
void k_swp(const float* __restrict__ x, const float* __restrict__ p,
           const int* __restrict__ mask,
           float* __restrict__ nump, float* __restrict__ denp){
  int b = blockIdx.x, sc = blockIdx.y;
  int s0 = sc * 32;
  int tid = threadIdx.x, wv = tid >> 6, ln = tid & 63;
  __shared__ float wf[32*20];          // [s][h] stride-20, 2.5 KB

  int hg = wv & 3, sq = wv >> 2;
  float acc[8][4];
  #pragma unroll
  for (int i=0; i<8; i++){ acc[i][0]=0.f; acc[i][1]=0.f; acc[i][2]=0.f; acc[i][3]=0.f; }

  #pragma unroll 1
  for (int kc=0; kc<4; kc++){
    int d = kc*256 + ln*4;
    const float* pb = p + (size_t)(b*NH + hg*4)*DIM + d;
    float4 pr0 = *(const float4*)(pb);
    float4 pr1 = *(const float4*)(pb +   (size_t)DIM);
    float4 pr2 = *(const float4*)(pb + 2*(size_t)DIM);
    float4 pr3 = *(const float4*)(pb + 3*(size_t)DIM);
    const float* xb = x + (size_t)(b*SEQ + s0 + sq*8)*DIM + d;
    #pragma unroll
    for (int sb=0; sb<8; sb+=4){
      float4 xr[4];
      #pragma unroll
      for (int u=0; u<4; u++)
        xr[u] = *(const float4*)(xb + (size_t)(sb+u)*DIM);
      #pragma unroll
      for (int u=0; u<4; u++){
        acc[sb+u][0] += xr[u].x*pr0.x + xr[u].y*pr0.y + xr[u].z*pr0.z + xr[u].w*pr0.w;
        acc[sb+u][1] += xr[u].x*pr1.x + xr[u].y*pr1.y + xr[u].z*pr1.z + xr[u].w*pr1.w;
        acc[sb+u][2] += xr[u].x*pr2.x + xr[u].y*pr2.y + xr[u].z*pr2.z + xr[u].w*pr2.w;
        acc[sb+u][3] += xr[u].x*pr3.x + xr[u].y*pr3.y + xr[u].z*pr3.z + xr[u].w*pr3.w;
      }
    }
  }
  // folding reduction: value v = si*4+hj; A(v) aliases acc.
  // Level k (offset 1<<k): keep values whose bit k == lane bit k; receive
  // partner's copy of the kept value, add. After 5 levels lane holds v=ln&31
  // summed over its 32-lane group; offset-32 add completes all 64 lanes.
#define A(v) acc[(v)>>2][(v)&3]
  {
    float c16[16], c8[8], c4[4], c2[2], c1;
    int bb;
    bb = ln & 1;
    #pragma unroll
    for (int i=0;i<16;i++){
      float keep = bb ? A(2*i+1) : A(2*i);
      float send = bb ? A(2*i)   : A(2*i+1);
      c16[i] = keep + __shfl_xor(send, 1, 64);
    }
    bb = (ln>>1) & 1;
    #pragma unroll
    for (int i=0;i<8;i++){
      float keep = bb ? c16[2*i+1] : c16[2*i];
      float send = bb ? c16[2*i]   : c16[2*i+1];
      c8[i] = keep + __shfl_xor(send, 2, 64);
    }
    bb = (ln>>2) & 1;
    #pragma unroll
    for (int i=0;i<4;i++){
      float keep = bb ? c8[2*i+1] : c8[2*i];
      float send = bb ? c8[2*i]   : c8[2*i+1];
      c4[i] = keep + __shfl_xor(send, 4, 64);
    }
    bb = (ln>>3) & 1;
    #pragma unroll
    for (int i=0;i<2;i++){
      float keep = bb ? c4[2*i+1] : c4[2*i];
      float send = bb ? c4[2*i]   : c4[2*i+1];
      c2[i] = keep + __shfl_xor(send, 8, 64);
    }
    bb = (ln>>4) & 1;
    {
      float keep = bb ? c2[1] : c2[0];
      float send = bb ? c2[0] : c2[1];
      c1 = keep + __shfl_xor(send, 16, 64);
    }
    c1 += __shfl_xor(c1, 32, 64);
    if (ln < 32){                      // v = ln&31: si = (ln>>2)&7, hj = ln&3
      wf[(sq*8 + ((ln>>2)&7))*20 + hg*4 + (ln&3)] = c1;
    }
  }
#undef A
  __syncthreads();
  if (tid < 512){                      // phase B: e = mask * exp(score), in place
    int s = tid >> 4, h = tid & 15;
    float sv = wf[s*20 + h];
    wf[s*20 + h] = mask[b*SEQ + s0 + s] ? __expf(sv) : 0.f;
  }
  __syncthreads();
  if (tid < 16){                       // den partial per head (once per (b,sc))
    float dsum = 0.f;
    #pragma unroll
    for (int ss=0; ss<32; ss++) dsum += wf[ss*20 + tid];
    denp[(sc*BS + b)*NH + tid] = dsum;
  }
  // phase C: weighted pool. wave wv -> heads hg2*4..+3, d chunk dc*256..+255.
  int hg2 = wv >> 2, dc = wv & 3;
  int d = dc*256 + ln*4;
  const float* xbase = x + (size_t)(b*SEQ + s0)*DIM + d;
  float4 a0={0,0,0,0}, a1={0,0,0,0}, a2={0,0,0,0}, a3={0,0,0,0};
  #pragma unroll 1
  for (int sb=0; sb<32; sb+=8){
    float4 xq[8];
    #pragma unroll
    for (int u=0; u<8; u++)
      xq[u] = *(const float4*)(xbase + (size_t)(sb+u)*DIM);   // 8 loads in flight
    #pragma unroll
    for (int u=0; u<8; u++){
      float4 w = *(const float4*)(wf + (sb+u)*20 + hg2*4);   // wave-uniform bcast
      a0.x += xq[u].x*w.x; a0.y += xq[u].y*w.x; a0.z += xq[u].z*w.x; a0.w += xq[u].w*w.x;
      a1.x += xq[u].x*w.y; a1.y += xq[u].y*w.y; a1.z += xq[u].z*w.y; a1.w += xq[u].w*w.y;
      a2.x += xq[u].x*w.z; a2.y += xq[u].y*w.z; a2.z += xq[u].z*w.z; a2.w += xq[u].w*w.z;
      a3.x += xq[u].x*w.w; a3.y += xq[u].y*w.w; a3.z += xq[u].z*w.w; a3.w += xq[u].w*w.w;
    }
  }
  float* dst = nump + (size_t)sc*(BS*NH*DIM) + (size_t)(b*NH + hg2*4)*DIM + d;
  *(float4*)(dst                 ) = a0;
  *(float4*)(dst +   (size_t)DIM ) = a1;
  *(float4*)(dst + 2*(size_t)DIM ) = a2;
  *(float4*)(dst + 3*(size_t)DIM ) = a3;
}

// ---------------- K3: xw[b,h,d] = sum_sc num / sum_sc den ------------------
__global__ void k_xwred(const float* __restrict__ nump, const float* __restrict__ denp,
                        float* __restrict__ xw){
  int id = blockIdx.x*256 + threadIdx.x;   // 512 blocks -> 131072 ids
  int bh = id >> 10;                        // b*NH + h
  int b = bh >> 4, h = bh & 15;
  float den = 0.f;
  #pragma unroll
  for (int scn=0; scn<32; scn++) den += denp[(scn*BS + b)*NH + h];
  float num = 0.f;
  #pragma unroll
  for (int scn=0; scn<32; scn++) num += nump[(size_t)scn*(BS*NH*DIM) + id];
  xw[id] = num / den;
}

// ---------------- K4: ctx[b,jo] = xw[b,h(jo),:].vw[jo,:] + vb[jo] ----------
__global__ void k_ctx(const float* __restrict__ xw, const float* __restrict__ vw,
                      const float* __restrict__ vb, float* __restrict__ ctx){
  int wv = threadIdx.x >> 6, ln = threadIdx.x & 63;
  int jo = blockIdx.x*4 + wv;
  int h  = jo >> 6;
  float acc[BS] = {0,0,0,0,0,0,0,0};
  #pragma unroll
  for (int i=0; i<4; i++){
    int d = ln*4 + 256*i;
    float4 vv = *(const float4*)(vw + (size_t)jo*DIM + d);
    #pragma unroll
    for (int b=0; b<BS; b++){
      float4 xv = *(const float4*)(xw + (size_t)(b*NH + h)*DIM + d);
      acc[b] += vv.x*xv.x + vv.y*xv.y + vv.z*xv.z + vv.w*xv.w;
    }
  }
  #pragma unroll
  for (int off=32; off>=1; off>>=1){
    #pragma unroll
    for (int b=0; b<BS; b++) acc[b] += __shfl_down(acc[b], off, 64);
  }
  if (ln == 0){
    float bias = vb[jo];
    #pragma unroll
    for (int b=0; b<BS; b++) ctx[b*DIM + jo] = acc[b] + bias;
  }
}

// ---------------- K5: out_row[b,i] = ctx[b,:].ow[i,:] + ob[i] ----------------
__global__ void k_outrow(const float* __restrict__ ctx, const float* __restrict__ ow,
                         const float* __restrict__ ob, float* __restrict__ outr){
  int wv = threadIdx.x >> 6, ln = threadIdx.x & 63;
  int io = blockIdx.x*4 + wv;
  float acc[BS] = {0,0,0,0,0,0,0,0};
  #pragma unroll
  for (int i=0; i<4; i++){
    int d = ln*4 + 256*i;
    float4 wt = *(const float4*)(ow + (size_t)io*DIM + d);
    #pragma unroll
    for (int b=0; b<BS; b++){
      float4 cv = *(const float4*)(ctx + b*DIM + d);
      acc[b] += wt.x*cv.x + wt.y*cv.y + wt.z*cv.z + wt.w*cv.w;
    }
  }
  #pragma unroll
  for (int off=32; off>=1; off>>=1){
    #pragma unroll
    for (int b=0; b<BS; b++) acc[b] += __shfl_down(acc[b], off, 64);
  }
  if (ln == 0){
    float bias = ob[io];
    #pragma unroll
    for (int b=0; b<BS; b++) outr[b*DIM + io] = acc[b] + bias;
  }
}

// ---------------- K6: out[b,s,:] = LN(out_row[b]+x[b,s,:])*g + beta ---------
__global__ void k_ln(const float* __restrict__ x, const float* __restrict__ outr,
                     const float* __restrict__ g, const float* __restrict__ bt,
                     float* __restrict__ out){
  int row = blockIdx.x;
  int b = row >> 10;
  size_t base = (size_t)row * DIM;
  int tid = threadIdx.x;
  float4 xv = ((const float4*)(x + base))[tid];
  float4 ov = ((const float4*)(outr + (size_t)b*DIM))[tid];
  float4 h;
  h.x = xv.x + ov.x; h.y = xv.y + ov.y; h.z = xv.z + ov.z; h.w = xv.w + ov.w;
  float s  = h.x + h.y + h.z + h.w;
  float s2 = h.x*h.x + h.y*h.y + h.z*h.z + h.w*h.w;
  #pragma unroll
  for (int off=32; off>=1; off>>=1){
    s  += __shfl_xor(s,  off, 64);
    s2 += __shfl_xor(s2, off, 64);
  }
  __shared__ float r1[4], r2[4];
  int wv = tid >> 6, ln = tid & 63;
  if (ln == 0){ r1[wv] = s; r2[wv] = s2; }
  __syncthreads();
  s  = r1[0] + r1[1] + r1[2] + r1[3];
  s2 = r2[0] + r2[1] + r2[2] + r2[3];
  float mu   = s  * (1.f/1024.f);
  float var  = s2 * (1.f/1024.f) - mu*mu;
  float rstd = rsqrtf(var + 1e-12f);
  float4 gv = ((const float4*)g)[tid];
  float4 bv = ((const float4*)bt)[tid];
  float4 y;
  y.x = (h.x - mu)*rstd*gv.x + bv.x;
  y.y = (h.y - mu)*rstd*gv.y + bv.y;
  y.z = (h.z - mu)*rstd*gv.z + bv.z;
  y.w = (h.w - mu)*rstd*gv.w + bv.w;
  ((float4*)(out + base))[tid] = y;
}

extern "C" void kernel_launch(void* const* d_in, const int* in_sizes, int n_in,
                              void* d_out, int out_size, void* d_ws, size_t ws_size,
                              hipStream_t stream) {
  const float* x    = (const float*)d_in[0];
  const float* xnb  = (const float*)d_in[1];
  const int*   mask = (const int*  )d_in[2];
  const float* nm   = (const float*)d_in[3];
  const float* qw   = (const float*)d_in[4];
  const float* qb   = (const float*)d_in[5];
  const float* kw   = (const float*)d_in[6];
  // d_in[7] = kb: softmax-invariant constant, unused
  const float* vw   = (const float*)d_in[8];
  const float* vb   = (const float*)d_in[9];
  const float* ow   = (const float*)d_in[10];
  const float* ob   = (const float*)d_in[11];
  const float* lng  = (const float*)d_in[12];
  const float* lnb  = (const float*)d_in[13];
  float* out = (float*)d_out;

  float* ws   = (float*)d_ws;              // ~17.9 MB of ~256 MB ws
  float* p    = ws + OF_P;
  float* nump = ws + OF_NUMP;              // 32 s-chunk slabs
  float* denp = ws + OF_DENP;              // 32 x 128
  float* xw   = ws + OF_XW;
  float* ctx  = ws + OF_CTX;
  float* outr = ws + OF_OUTR;

  k_prep  <<<128,             256,  0, stream>>>(xnb, nm, qw, qb, kw, p);
  k_swp   <<<dim3(BS,32),     1024, 0, stream>>>(x, p, mask, nump, denp);
  k_xwred <<<512,             256,  0, stream>>>(nump, denp, xw);
  k_ctx   <<<256,             256,  0, stream>>>(xw, vw, vb, ctx);
  k_outrow<<<256,             256,  0, stream>>>(ctx, ow, ob, outr);
  k_ln    <<<BS*SEQ,          256,  0, stream>>>(x, outr, lng, lnb, out);
}